// Round 1
// baseline (145.804 us; speedup 1.0000x reference)
//
#include <hip/hip_runtime.h>
#include <hip/hip_bf16.h>

typedef __bf16 bf16_t;
typedef __bf16 bf16x8 __attribute__((ext_vector_type(8)));
typedef float f32x4 __attribute__((ext_vector_type(4)));

#define MFMA16(A,B,C) __builtin_amdgcn_mfma_f32_16x16x32_bf16(A,B,C,0,0,0)

constexpr int Bb = 4, Ll = 2048, Hh = 8, Ee = 64, Dd = 64;
constexpr int BQ = 64;    // q rows per block (4 waves x 16)
constexpr int BKV = 64;   // kv rows per tile
constexpr int LDP = 72;   // padded LDS row stride (bf16 elems), 144 B = 16B-aligned, odd dword stride
constexpr int MS = 128;   // band half-width (masked to -inf inside band)

static __device__ __forceinline__ bf16x8 cvt8(float4 a, float4 b) {
    bf16x8 t;
    t[0] = (bf16_t)a.x; t[1] = (bf16_t)a.y; t[2] = (bf16_t)a.z; t[3] = (bf16_t)a.w;
    t[4] = (bf16_t)b.x; t[5] = (bf16_t)b.y; t[6] = (bf16_t)b.z; t[7] = (bf16_t)b.w;
    return t;
}

__global__ __launch_bounds__(256, 2) void fattn(const float* __restrict__ Q,
                                                const float* __restrict__ K,
                                                const float* __restrict__ V,
                                                float* __restrict__ O) {
    __shared__ __align__(16) bf16_t Klds[BKV][LDP];
    __shared__ __align__(16) bf16_t Vtlds[Dd][LDP];
    __shared__ __align__(16) bf16_t Plds[4][16][LDP];

    const int tid = threadIdx.x;
    const int wv  = tid >> 6;
    const int ln  = tid & 63;
    const int l15 = ln & 15;
    const int g   = ln >> 4;

    const int nqt = Ll / BQ;                 // 32
    const int bid = blockIdx.x;
    const int qt  = bid % nqt;
    const int bh  = bid / nqt;
    const int b   = bh >> 3;                 // H = 8
    const int h   = bh & 7;
    const int q0  = qt * BQ;

    const float SCL2 = 0.125f * 1.44269504f; // (1/sqrt(64)) * log2(e)

    // ---- Q fragments (A-operand layout: row = lane%16, k-slot = 8*(lane/16)+e) ----
    bf16x8 qf[2];
    {
        const float* qp = Q + (((size_t)(b * Ll + q0 + wv * 16 + l15)) * Hh + h) * Ee + g * 8;
        #pragma unroll
        for (int ks = 0; ks < 2; ++ks) {
            float4 f0 = *(const float4*)(qp + 32 * ks);
            float4 f1 = *(const float4*)(qp + 32 * ks + 4);
            qf[ks] = cvt8(f0, f1);
        }
    }

    f32x4 acc[4];
    #pragma unroll
    for (int ct = 0; ct < 4; ++ct) acc[ct] = (f32x4){0.f, 0.f, 0.f, 0.f};
    float m2[4], lsum[4];
    #pragma unroll
    for (int r = 0; r < 4; ++r) { m2[r] = -1e30f; lsum[r] = 0.f; }

    for (int k0 = 0; k0 < Ll; k0 += BKV) {
        const int dd = k0 - q0;
        if (dd >= -64 && dd <= 64) continue;          // tile fully inside the band -> all masked
        const bool needmask = (dd == 128) || (dd == -128);

        __syncthreads();  // protect LDS from previous iteration's readers
        {
            // cooperative stage: 256 thr, each loads 16 floats of K and V
            const int j  = tid >> 2;
            const int c0 = (tid & 3) << 4;
            const float* kp = K + (((size_t)(b * Ll + k0 + j)) * Hh + h) * Ee + c0;
            const float* vp = V + (((size_t)(b * Ll + k0 + j)) * Hh + h) * Dd + c0;
            float4 a0 = ((const float4*)kp)[0], a1 = ((const float4*)kp)[1];
            float4 a2 = ((const float4*)kp)[2], a3 = ((const float4*)kp)[3];
            *(bf16x8*)&Klds[j][c0]     = cvt8(a0, a1);
            *(bf16x8*)&Klds[j][c0 + 8] = cvt8(a2, a3);
            float4 b0 = ((const float4*)vp)[0], b1 = ((const float4*)vp)[1];
            float4 b2 = ((const float4*)vp)[2], b3 = ((const float4*)vp)[3];
            Vtlds[c0 +  0][j] = (bf16_t)b0.x; Vtlds[c0 +  1][j] = (bf16_t)b0.y;
            Vtlds[c0 +  2][j] = (bf16_t)b0.z; Vtlds[c0 +  3][j] = (bf16_t)b0.w;
            Vtlds[c0 +  4][j] = (bf16_t)b1.x; Vtlds[c0 +  5][j] = (bf16_t)b1.y;
            Vtlds[c0 +  6][j] = (bf16_t)b1.z; Vtlds[c0 +  7][j] = (bf16_t)b1.w;
            Vtlds[c0 +  8][j] = (bf16_t)b2.x; Vtlds[c0 +  9][j] = (bf16_t)b2.y;
            Vtlds[c0 + 10][j] = (bf16_t)b2.z; Vtlds[c0 + 11][j] = (bf16_t)b2.w;
            Vtlds[c0 + 12][j] = (bf16_t)b3.x; Vtlds[c0 + 13][j] = (bf16_t)b3.y;
            Vtlds[c0 + 14][j] = (bf16_t)b3.z; Vtlds[c0 + 15][j] = (bf16_t)b3.w;
        }
        __syncthreads();

        // ---- S = Q K^T : wave computes 16x64, D-layout row=(lane>>4)*4+r, col=16*ct+lane&15
        f32x4 s[4];
        #pragma unroll
        for (int ct = 0; ct < 4; ++ct) {
            f32x4 z = (f32x4){0.f, 0.f, 0.f, 0.f};
            #pragma unroll
            for (int ks = 0; ks < 2; ++ks) {
                bf16x8 kf = *(const bf16x8*)&Klds[ct * 16 + l15][ks * 32 + g * 8];
                z = MFMA16(qf[ks], kf, z);
            }
            s[ct] = z;
        }

        // ---- mask + online softmax (log2 domain) ----
        float lg[4][4];
        #pragma unroll
        for (int ct = 0; ct < 4; ++ct)
            #pragma unroll
            for (int r = 0; r < 4; ++r)
                lg[ct][r] = s[ct][r] * SCL2;

        if (needmask) {
            const int irow = q0 + wv * 16 + g * 4;
            #pragma unroll
            for (int ct = 0; ct < 4; ++ct) {
                const int j = k0 + ct * 16 + l15;
                #pragma unroll
                for (int r = 0; r < 4; ++r) {
                    int diff = irow + r - j;
                    diff = diff < 0 ? -diff : diff;
                    if (diff < MS) lg[ct][r] = -1e30f;
                }
            }
        }

        #pragma unroll
        for (int r = 0; r < 4; ++r) {
            float mx = fmaxf(fmaxf(lg[0][r], lg[1][r]), fmaxf(lg[2][r], lg[3][r]));
            #pragma unroll
            for (int off = 1; off < 16; off <<= 1) mx = fmaxf(mx, __shfl_xor(mx, off));
            const float mnew = fmaxf(m2[r], mx);
            const float c = exp2f(m2[r] - mnew);
            m2[r] = mnew;
            #pragma unroll
            for (int ct = 0; ct < 4; ++ct) acc[ct][r] *= c;
            float ps = 0.f;
            #pragma unroll
            for (int ct = 0; ct < 4; ++ct) {
                float p = exp2f(lg[ct][r] - mnew);
                bf16_t pb = (bf16_t)p;
                Plds[wv][g * 4 + r][ct * 16 + l15] = pb;
                ps += (float)pb;   // sum what we actually multiply by
            }
            #pragma unroll
            for (int off = 1; off < 16; off <<= 1) ps += __shfl_xor(ps, off);
            lsum[r] = lsum[r] * c + ps;
        }

        __syncthreads();  // round-0 insurance: P visible before A-frag reads (A/B-removable)

        // ---- O += P V ----
        #pragma unroll
        for (int ks = 0; ks < 2; ++ks) {
            bf16x8 pf = *(const bf16x8*)&Plds[wv][l15][ks * 32 + g * 8];
            #pragma unroll
            for (int ct = 0; ct < 4; ++ct) {
                bf16x8 vf = *(const bf16x8*)&Vtlds[ct * 16 + l15][ks * 32 + g * 8];
                acc[ct] = MFMA16(pf, vf, acc[ct]);
            }
        }
    }

    // ---- epilogue: O = acc / l ----
    #pragma unroll
    for (int r = 0; r < 4; ++r) {
        const float inv = 1.0f / lsum[r];
        const size_t row = (size_t)(b * Ll + q0 + wv * 16 + g * 4 + r);
        float* op = O + (row * Hh + h) * Dd;
        #pragma unroll
        for (int ct = 0; ct < 4; ++ct)
            op[ct * 16 + l15] = acc[ct][r] * inv;
    }
}

extern "C" void kernel_launch(void* const* d_in, const int* in_sizes, int n_in,
                              void* d_out, int out_size, void* d_ws, size_t ws_size,
                              hipStream_t stream) {
    const float* Q = (const float*)d_in[0];
    const float* K = (const float*)d_in[1];
    const float* V = (const float*)d_in[2];
    float* O = (float*)d_out;
    const int nblocks = Bb * Hh * (Ll / BQ);  // 1024
    fattn<<<dim3(nblocks), dim3(256), 0, stream>>>(Q, K, V, O);
}

// Round 2
// 133.534 us; speedup vs baseline: 1.0919x; 1.0919x over previous
//
#include <hip/hip_runtime.h>
#include <hip/hip_bf16.h>

typedef __bf16 bf16_t;
typedef __bf16 bf16x8 __attribute__((ext_vector_type(8)));
typedef float f32x4 __attribute__((ext_vector_type(4)));

#define MFMA16(A,B,C) __builtin_amdgcn_mfma_f32_16x16x32_bf16(A,B,C,0,0,0)

constexpr int Bb = 4, Ll = 2048, Hh = 8, Ee = 64, Dd = 64;
constexpr int BQ = 64;    // q rows per block (4 waves x 16)
constexpr int BKV = 64;   // kv rows per tile
constexpr int LDP = 72;   // padded LDS row stride (bf16 elems)
constexpr int MS = 128;   // band half-width (masked to -inf inside band)

static __device__ __forceinline__ bf16x8 cvt8(float4 a, float4 b) {
    bf16x8 t;
    t[0] = (bf16_t)a.x; t[1] = (bf16_t)a.y; t[2] = (bf16_t)a.z; t[3] = (bf16_t)a.w;
    t[4] = (bf16_t)b.x; t[5] = (bf16_t)b.y; t[6] = (bf16_t)b.z; t[7] = (bf16_t)b.w;
    return t;
}

// ---------------- prep: Q/K [b,l,h,e] fp32 -> [b,h,l,e] bf16 ----------------
__global__ __launch_bounds__(256) void cvt_qk(const float* __restrict__ src,
                                              bf16_t* __restrict__ dst) {
    const int c = blockIdx.x * 256 + threadIdx.x;   // one 8-elem chunk
    const int e0 = (c & 7) * 8;
    const int h  = (c >> 3) & (Hh - 1);
    const int l  = (c >> 6) & (Ll - 1);
    const int b  = c >> 17;
    const float* s = src + ((((size_t)b * Ll + l) * Hh + h) * Ee + e0);
    float4 f0 = ((const float4*)s)[0];
    float4 f1 = ((const float4*)s)[1];
    *(bf16x8*)(dst + ((((size_t)b * Hh + h) * Ll + l) * Ee + e0)) = cvt8(f0, f1);
}

// -------- prep: V [b,l,h,d] fp32 -> Vt [b,h,tile,d,64] bf16 (transposed) ----
__global__ __launch_bounds__(256) void cvt_v(const float* __restrict__ V,
                                             bf16_t* __restrict__ Vt) {
    __shared__ bf16_t VL[Dd][LDP];
    const int bh = blockIdx.x >> 5;      // b*8+h
    const int t  = blockIdx.x & 31;      // k-tile index
    const int b = bh >> 3, h = bh & 7;
    {
        const int j  = threadIdx.x >> 2;
        const int d0 = (threadIdx.x & 3) * 16;
        const float* vp = V + (((size_t)(b * Ll + t * 64 + j)) * Hh + h) * Dd + d0;
        float4 x0 = ((const float4*)vp)[0], x1 = ((const float4*)vp)[1];
        float4 x2 = ((const float4*)vp)[2], x3 = ((const float4*)vp)[3];
        VL[d0 +  0][j] = (bf16_t)x0.x; VL[d0 +  1][j] = (bf16_t)x0.y;
        VL[d0 +  2][j] = (bf16_t)x0.z; VL[d0 +  3][j] = (bf16_t)x0.w;
        VL[d0 +  4][j] = (bf16_t)x1.x; VL[d0 +  5][j] = (bf16_t)x1.y;
        VL[d0 +  6][j] = (bf16_t)x1.z; VL[d0 +  7][j] = (bf16_t)x1.w;
        VL[d0 +  8][j] = (bf16_t)x2.x; VL[d0 +  9][j] = (bf16_t)x2.y;
        VL[d0 + 10][j] = (bf16_t)x2.z; VL[d0 + 11][j] = (bf16_t)x2.w;
        VL[d0 + 12][j] = (bf16_t)x3.x; VL[d0 + 13][j] = (bf16_t)x3.y;
        VL[d0 + 14][j] = (bf16_t)x3.z; VL[d0 + 15][j] = (bf16_t)x3.w;
    }
    __syncthreads();
    {
        const int d  = threadIdx.x >> 2;
        const int j0 = (threadIdx.x & 3) * 16;
        bf16x8 a0 = *(const bf16x8*)&VL[d][j0];
        bf16x8 a1 = *(const bf16x8*)&VL[d][j0 + 8];
        bf16_t* op = Vt + ((((size_t)bh * 32 + t) * 64 + d) * 64 + j0);
        *(bf16x8*)op = a0;
        *(bf16x8*)(op + 8) = a1;
    }
}

// ---------------- main attention (bf16 pre-converted inputs) ----------------
__global__ __launch_bounds__(256, 2) void fattn_bf(const bf16_t* __restrict__ Qb,
                                                   const bf16_t* __restrict__ Kb,
                                                   const bf16_t* __restrict__ Vt,
                                                   float* __restrict__ O) {
    __shared__ __align__(16) bf16_t Klds[BKV][LDP];
    __shared__ __align__(16) bf16_t Vtlds[Dd][LDP];
    __shared__ __align__(16) bf16_t Plds[4][16][LDP];

    const int tid = threadIdx.x;
    const int wv  = tid >> 6;
    const int ln  = tid & 63;
    const int l15 = ln & 15;
    const int g   = ln >> 4;

    const int nqt = Ll / BQ;                 // 32
    const int bid = blockIdx.x;
    const int qt  = bid % nqt;
    const int bh  = bid / nqt;
    const int b   = bh >> 3;
    const int h   = bh & 7;
    const int q0  = qt * BQ;

    const float SCL2 = 0.125f * 1.44269504f; // (1/sqrt(64)) * log2(e)

    // Q fragments (A layout: row = lane%16, k = 32*ks + 8*(lane/16) + e)
    bf16x8 qf[2];
    {
        const bf16_t* qp = Qb + ((((size_t)bh) * Ll + q0 + wv * 16 + l15) * Ee + g * 8);
        qf[0] = *(const bf16x8*)(qp);
        qf[1] = *(const bf16x8*)(qp + 32);
    }

    f32x4 acc[4];
    #pragma unroll
    for (int ct = 0; ct < 4; ++ct) acc[ct] = (f32x4){0.f, 0.f, 0.f, 0.f};
    float m2[4], lsum[4];
    #pragma unroll
    for (int r = 0; r < 4; ++r) { m2[r] = -1e30f; lsum[r] = 0.f; }

    // staging addresses: thread owns 16 contiguous bf16 (=1/256 of the 8KB tile)
    const int sj = tid >> 2;               // row within tile
    const int sc = (tid & 3) * 16;         // col within row
    const bf16_t* kbase = Kb + ((size_t)bh * Ll) * Ee;
    const bf16_t* vbase = Vt + ((size_t)bh * 32) * 64 * 64;

    for (int k0 = 0; k0 < Ll; k0 += BKV) {
        const int dd = k0 - q0;
        if (dd >= -64 && dd <= 64) continue;          // tile fully masked
        const bool needmask = (dd == 128) || (dd == -128);

        __syncthreads();  // protect LDS from previous iteration's readers
        {
            const bf16_t* kt = kbase + (size_t)k0 * Ee + tid * 16;
            const bf16_t* vt = vbase + (size_t)(k0 >> 6) * 4096 + tid * 16;
            bf16x8 ka = *(const bf16x8*)kt;
            bf16x8 kb2 = *(const bf16x8*)(kt + 8);
            bf16x8 va = *(const bf16x8*)vt;
            bf16x8 vb = *(const bf16x8*)(vt + 8);
            *(bf16x8*)&Klds[sj][sc]      = ka;
            *(bf16x8*)&Klds[sj][sc + 8]  = kb2;
            *(bf16x8*)&Vtlds[sj][sc]     = va;
            *(bf16x8*)&Vtlds[sj][sc + 8] = vb;
        }
        __syncthreads();

        // S = Q K^T : wave computes 16x64; D layout row=g*4+r, col=16*ct+l15
        f32x4 s[4];
        #pragma unroll
        for (int ct = 0; ct < 4; ++ct) {
            f32x4 z = (f32x4){0.f, 0.f, 0.f, 0.f};
            #pragma unroll
            for (int ks = 0; ks < 2; ++ks) {
                bf16x8 kf = *(const bf16x8*)&Klds[ct * 16 + l15][ks * 32 + g * 8];
                z = MFMA16(qf[ks], kf, z);
            }
            s[ct] = z;
        }

        float lg[4][4];
        #pragma unroll
        for (int ct = 0; ct < 4; ++ct)
            #pragma unroll
            for (int r = 0; r < 4; ++r)
                lg[ct][r] = s[ct][r] * SCL2;

        if (needmask) {
            const int irow = q0 + wv * 16 + g * 4;
            #pragma unroll
            for (int ct = 0; ct < 4; ++ct) {
                const int j = k0 + ct * 16 + l15;
                #pragma unroll
                for (int r = 0; r < 4; ++r) {
                    int diff = irow + r - j;
                    diff = diff < 0 ? -diff : diff;
                    if (diff < MS) lg[ct][r] = -1e30f;
                }
            }
        }

        #pragma unroll
        for (int r = 0; r < 4; ++r) {
            float mx = fmaxf(fmaxf(lg[0][r], lg[1][r]), fmaxf(lg[2][r], lg[3][r]));
            #pragma unroll
            for (int off = 1; off < 16; off <<= 1) mx = fmaxf(mx, __shfl_xor(mx, off));
            const float mnew = fmaxf(m2[r], mx);
            const float c = exp2f(m2[r] - mnew);
            m2[r] = mnew;
            #pragma unroll
            for (int ct = 0; ct < 4; ++ct) acc[ct][r] *= c;
            float ps = 0.f;
            #pragma unroll
            for (int ct = 0; ct < 4; ++ct) {
                float p = exp2f(lg[ct][r] - mnew);
                bf16_t pb = (bf16_t)p;
                Plds[wv][g * 4 + r][ct * 16 + l15] = pb;
                ps += (float)pb;
            }
            #pragma unroll
            for (int off = 1; off < 16; off <<= 1) ps += __shfl_xor(ps, off);
            lsum[r] = lsum[r] * c + ps;
        }

        // P is per-wave; intra-wave LDS ordering (lgkmcnt) suffices — no barrier.

        // O += P V
        #pragma unroll
        for (int ks = 0; ks < 2; ++ks) {
            bf16x8 pf = *(const bf16x8*)&Plds[wv][l15][ks * 32 + g * 8];
            #pragma unroll
            for (int ct = 0; ct < 4; ++ct) {
                bf16x8 vf = *(const bf16x8*)&Vtlds[ct * 16 + l15][ks * 32 + g * 8];
                acc[ct] = MFMA16(pf, vf, acc[ct]);
            }
        }
    }

    #pragma unroll
    for (int r = 0; r < 4; ++r) {
        const float inv = 1.0f / lsum[r];
        const size_t row = (size_t)(b * Ll + q0 + wv * 16 + g * 4 + r);
        float* op = O + (row * Hh + h) * Dd;
        #pragma unroll
        for (int ct = 0; ct < 4; ++ct)
            op[ct * 16 + l15] = acc[ct][r] * inv;
    }
}

// ---------------- fallback (round-0 kernel, fp32 inputs) ----------------
__global__ __launch_bounds__(256, 2) void fattn_f32(const float* __restrict__ Q,
                                                    const float* __restrict__ K,
                                                    const float* __restrict__ V,
                                                    float* __restrict__ O) {
    __shared__ __align__(16) bf16_t Klds[BKV][LDP];
    __shared__ __align__(16) bf16_t Vtlds[Dd][LDP];
    __shared__ __align__(16) bf16_t Plds[4][16][LDP];

    const int tid = threadIdx.x;
    const int wv  = tid >> 6;
    const int ln  = tid & 63;
    const int l15 = ln & 15;
    const int g   = ln >> 4;

    const int nqt = Ll / BQ;
    const int bid = blockIdx.x;
    const int qt  = bid % nqt;
    const int bh  = bid / nqt;
    const int b   = bh >> 3;
    const int h   = bh & 7;
    const int q0  = qt * BQ;

    const float SCL2 = 0.125f * 1.44269504f;

    bf16x8 qf[2];
    {
        const float* qp = Q + (((size_t)(b * Ll + q0 + wv * 16 + l15)) * Hh + h) * Ee + g * 8;
        #pragma unroll
        for (int ks = 0; ks < 2; ++ks) {
            float4 f0 = *(const float4*)(qp + 32 * ks);
            float4 f1 = *(const float4*)(qp + 32 * ks + 4);
            qf[ks] = cvt8(f0, f1);
        }
    }

    f32x4 acc[4];
    #pragma unroll
    for (int ct = 0; ct < 4; ++ct) acc[ct] = (f32x4){0.f, 0.f, 0.f, 0.f};
    float m2[4], lsum[4];
    #pragma unroll
    for (int r = 0; r < 4; ++r) { m2[r] = -1e30f; lsum[r] = 0.f; }

    for (int k0 = 0; k0 < Ll; k0 += BKV) {
        const int dd = k0 - q0;
        if (dd >= -64 && dd <= 64) continue;
        const bool needmask = (dd == 128) || (dd == -128);

        __syncthreads();
        {
            const int j  = tid >> 2;
            const int c0 = (tid & 3) << 4;
            const float* kp = K + (((size_t)(b * Ll + k0 + j)) * Hh + h) * Ee + c0;
            const float* vp = V + (((size_t)(b * Ll + k0 + j)) * Hh + h) * Dd + c0;
            float4 a0 = ((const float4*)kp)[0], a1 = ((const float4*)kp)[1];
            float4 a2 = ((const float4*)kp)[2], a3 = ((const float4*)kp)[3];
            *(bf16x8*)&Klds[j][c0]     = cvt8(a0, a1);
            *(bf16x8*)&Klds[j][c0 + 8] = cvt8(a2, a3);
            float4 b0 = ((const float4*)vp)[0], b1 = ((const float4*)vp)[1];
            float4 b2 = ((const float4*)vp)[2], b3 = ((const float4*)vp)[3];
            Vtlds[c0 +  0][j] = (bf16_t)b0.x; Vtlds[c0 +  1][j] = (bf16_t)b0.y;
            Vtlds[c0 +  2][j] = (bf16_t)b0.z; Vtlds[c0 +  3][j] = (bf16_t)b0.w;
            Vtlds[c0 +  4][j] = (bf16_t)b1.x; Vtlds[c0 +  5][j] = (bf16_t)b1.y;
            Vtlds[c0 +  6][j] = (bf16_t)b1.z; Vtlds[c0 +  7][j] = (bf16_t)b1.w;
            Vtlds[c0 +  8][j] = (bf16_t)b2.x; Vtlds[c0 +  9][j] = (bf16_t)b2.y;
            Vtlds[c0 + 10][j] = (bf16_t)b2.z; Vtlds[c0 + 11][j] = (bf16_t)b2.w;
            Vtlds[c0 + 12][j] = (bf16_t)b3.x; Vtlds[c0 + 13][j] = (bf16_t)b3.y;
            Vtlds[c0 + 14][j] = (bf16_t)b3.z; Vtlds[c0 + 15][j] = (bf16_t)b3.w;
        }
        __syncthreads();

        f32x4 s[4];
        #pragma unroll
        for (int ct = 0; ct < 4; ++ct) {
            f32x4 z = (f32x4){0.f, 0.f, 0.f, 0.f};
            #pragma unroll
            for (int ks = 0; ks < 2; ++ks) {
                bf16x8 kf = *(const bf16x8*)&Klds[ct * 16 + l15][ks * 32 + g * 8];
                z = MFMA16(qf[ks], kf, z);
            }
            s[ct] = z;
        }

        float lg[4][4];
        #pragma unroll
        for (int ct = 0; ct < 4; ++ct)
            #pragma unroll
            for (int r = 0; r < 4; ++r)
                lg[ct][r] = s[ct][r] * SCL2;

        if (needmask) {
            const int irow = q0 + wv * 16 + g * 4;
            #pragma unroll
            for (int ct = 0; ct < 4; ++ct) {
                const int j = k0 + ct * 16 + l15;
                #pragma unroll
                for (int r = 0; r < 4; ++r) {
                    int diff = irow + r - j;
                    diff = diff < 0 ? -diff : diff;
                    if (diff < MS) lg[ct][r] = -1e30f;
                }
            }
        }

        #pragma unroll
        for (int r = 0; r < 4; ++r) {
            float mx = fmaxf(fmaxf(lg[0][r], lg[1][r]), fmaxf(lg[2][r], lg[3][r]));
            #pragma unroll
            for (int off = 1; off < 16; off <<= 1) mx = fmaxf(mx, __shfl_xor(mx, off));
            const float mnew = fmaxf(m2[r], mx);
            const float c = exp2f(m2[r] - mnew);
            m2[r] = mnew;
            #pragma unroll
            for (int ct = 0; ct < 4; ++ct) acc[ct][r] *= c;
            float ps = 0.f;
            #pragma unroll
            for (int ct = 0; ct < 4; ++ct) {
                float p = exp2f(lg[ct][r] - mnew);
                bf16_t pb = (bf16_t)p;
                Plds[wv][g * 4 + r][ct * 16 + l15] = pb;
                ps += (float)pb;
            }
            #pragma unroll
            for (int off = 1; off < 16; off <<= 1) ps += __shfl_xor(ps, off);
            lsum[r] = lsum[r] * c + ps;
        }

        __syncthreads();

        #pragma unroll
        for (int ks = 0; ks < 2; ++ks) {
            bf16x8 pf = *(const bf16x8*)&Plds[wv][l15][ks * 32 + g * 8];
            #pragma unroll
            for (int ct = 0; ct < 4; ++ct) {
                bf16x8 vf = *(const bf16x8*)&Vtlds[ct * 16 + l15][ks * 32 + g * 8];
                acc[ct] = MFMA16(pf, vf, acc[ct]);
            }
        }
    }

    #pragma unroll
    for (int r = 0; r < 4; ++r) {
        const float inv = 1.0f / lsum[r];
        const size_t row = (size_t)(b * Ll + q0 + wv * 16 + g * 4 + r);
        float* op = O + (row * Hh + h) * Dd;
        #pragma unroll
        for (int ct = 0; ct < 4; ++ct)
            op[ct * 16 + l15] = acc[ct][r] * inv;
    }
}

extern "C" void kernel_launch(void* const* d_in, const int* in_sizes, int n_in,
                              void* d_out, int out_size, void* d_ws, size_t ws_size,
                              hipStream_t stream) {
    const float* Q = (const float*)d_in[0];
    const float* K = (const float*)d_in[1];
    const float* V = (const float*)d_in[2];
    float* O = (float*)d_out;
    const int nblocks = Bb * Hh * (Ll / BQ);  // 1024

    const size_t nelem = (size_t)Bb * Hh * Ll * Ee;      // 4.19M per tensor
    const size_t need  = nelem * 2 * 3;                  // 3 bf16 tensors

    if (ws_size >= need) {
        bf16_t* Qb = (bf16_t*)d_ws;
        bf16_t* Kb = Qb + nelem;
        bf16_t* Vt = Kb + nelem;
        const int cblocks = (int)(nelem / 8 / 256);      // 2048
        cvt_qk<<<dim3(cblocks), dim3(256), 0, stream>>>(Q, Qb);
        cvt_qk<<<dim3(cblocks), dim3(256), 0, stream>>>(K, Kb);
        cvt_v<<<dim3(Bb * Hh * 32), dim3(256), 0, stream>>>(V, Vt);
        fattn_bf<<<dim3(nblocks), dim3(256), 0, stream>>>(Qb, Kb, Vt, O);
    } else {
        fattn_f32<<<dim3(nblocks), dim3(256), 0, stream>>>(Q, K, V, O);
    }
}

// Round 3
// 85.799 us; speedup vs baseline: 1.6994x; 1.5564x over previous
//
#include <hip/hip_runtime.h>
#include <hip/hip_bf16.h>

typedef __bf16 bf16_t;
typedef __bf16 bf16x8 __attribute__((ext_vector_type(8)));
typedef float f32x4 __attribute__((ext_vector_type(4)));

#define MFMA16(A,B,C) __builtin_amdgcn_mfma_f32_16x16x32_bf16(A,B,C,0,0,0)

constexpr int Bb = 4, Ll = 2048, Hh = 8, Ee = 64, Dd = 64;
constexpr int BQ = 64;    // q rows per block (4 waves x 16)
constexpr int BKV = 64;   // kv rows per tile
constexpr int LDP = 72;   // padded stride for fallback kernel only
constexpr int MS = 128;   // band half-width (masked to -inf inside band)

// XOR swizzle: within a 64-elem (128B) row, permute 8-elem (16B) chunks by row&7.
// Spreads the 16-row column-slice reads across all banks (T2 / m214 G4 pattern).
#define SWZ(row, col) (((row) * 64 + ((col) ^ (((row) & 7) << 3))))

static __device__ __forceinline__ bf16x8 cvt8(float4 a, float4 b) {
    bf16x8 t;
    t[0] = (bf16_t)a.x; t[1] = (bf16_t)a.y; t[2] = (bf16_t)a.z; t[3] = (bf16_t)a.w;
    t[4] = (bf16_t)b.x; t[5] = (bf16_t)b.y; t[6] = (bf16_t)b.z; t[7] = (bf16_t)b.w;
    return t;
}

// ---------------- prep: Q/K [b,l,h,e] fp32 -> [b,h,l,e] bf16 (scaled) -------
__global__ __launch_bounds__(256) void cvt_qk(const float* __restrict__ src,
                                              bf16_t* __restrict__ dst,
                                              float scale) {
    const int c = blockIdx.x * 256 + threadIdx.x;   // one 8-elem chunk
    const int e0 = (c & 7) * 8;
    const int h  = (c >> 3) & (Hh - 1);
    const int l  = (c >> 6) & (Ll - 1);
    const int b  = c >> 17;
    const float* s = src + ((((size_t)b * Ll + l) * Hh + h) * Ee + e0);
    float4 f0 = ((const float4*)s)[0];
    float4 f1 = ((const float4*)s)[1];
    f0.x *= scale; f0.y *= scale; f0.z *= scale; f0.w *= scale;
    f1.x *= scale; f1.y *= scale; f1.z *= scale; f1.w *= scale;
    *(bf16x8*)(dst + ((((size_t)b * Hh + h) * Ll + l) * Ee + e0)) = cvt8(f0, f1);
}

// -------- prep: V [b,l,h,d] fp32 -> Vt [b,h,tile,d,64] bf16 (transposed) ----
__global__ __launch_bounds__(256) void cvt_v(const float* __restrict__ V,
                                             bf16_t* __restrict__ Vt) {
    __shared__ bf16_t VL[Dd][LDP];
    const int bh = blockIdx.x >> 5;      // b*8+h
    const int t  = blockIdx.x & 31;      // k-tile index
    const int b = bh >> 3, h = bh & 7;
    {
        const int j  = threadIdx.x >> 2;
        const int d0 = (threadIdx.x & 3) * 16;
        const float* vp = V + (((size_t)(b * Ll + t * 64 + j)) * Hh + h) * Dd + d0;
        float4 x0 = ((const float4*)vp)[0], x1 = ((const float4*)vp)[1];
        float4 x2 = ((const float4*)vp)[2], x3 = ((const float4*)vp)[3];
        VL[d0 +  0][j] = (bf16_t)x0.x; VL[d0 +  1][j] = (bf16_t)x0.y;
        VL[d0 +  2][j] = (bf16_t)x0.z; VL[d0 +  3][j] = (bf16_t)x0.w;
        VL[d0 +  4][j] = (bf16_t)x1.x; VL[d0 +  5][j] = (bf16_t)x1.y;
        VL[d0 +  6][j] = (bf16_t)x1.z; VL[d0 +  7][j] = (bf16_t)x1.w;
        VL[d0 +  8][j] = (bf16_t)x2.x; VL[d0 +  9][j] = (bf16_t)x2.y;
        VL[d0 + 10][j] = (bf16_t)x2.z; VL[d0 + 11][j] = (bf16_t)x2.w;
        VL[d0 + 12][j] = (bf16_t)x3.x; VL[d0 + 13][j] = (bf16_t)x3.y;
        VL[d0 + 14][j] = (bf16_t)x3.z; VL[d0 + 15][j] = (bf16_t)x3.w;
    }
    __syncthreads();
    {
        const int d  = threadIdx.x >> 2;
        const int j0 = (threadIdx.x & 3) * 16;
        bf16x8 a0 = *(const bf16x8*)&VL[d][j0];
        bf16x8 a1 = *(const bf16x8*)&VL[d][j0 + 8];
        bf16_t* op = Vt + ((((size_t)bh * 32 + t) * 64 + d) * 64 + j0);
        *(bf16x8*)op = a0;
        *(bf16x8*)(op + 8) = a1;
    }
}

// ---------------- main attention (bf16 pre-converted, fixed-max softmax) ----
__global__ __launch_bounds__(256, 4) void fattn_bf(const bf16_t* __restrict__ Qb,
                                                   const bf16_t* __restrict__ Kb,
                                                   const bf16_t* __restrict__ Vt,
                                                   float* __restrict__ O) {
    __shared__ __align__(16) bf16_t Klds[64 * 64];
    __shared__ __align__(16) bf16_t Vtlds[64 * 64];
    __shared__ __align__(16) bf16_t Plds[4 * 16 * 64];

    const int tid = threadIdx.x;
    const int wv  = tid >> 6;
    const int ln  = tid & 63;
    const int l15 = ln & 15;
    const int g   = ln >> 4;

    const int nqt = Ll / BQ;                 // 32
    const int bid = blockIdx.x;
    const int qt  = bid % nqt;
    const int bh  = bid / nqt;
    const int b   = bh >> 3;
    const int h   = bh & 7;
    const int q0  = qt * BQ;

    // Q fragments (A layout: row = lane%16, k = 32*ks + 8*(lane/16) + e).
    // Qb is pre-scaled by (1/sqrt(64))*log2(e), so S comes out in exp2 domain.
    bf16x8 qf[2];
    {
        const bf16_t* qp = Qb + ((((size_t)bh) * Ll + q0 + wv * 16 + l15) * Ee + g * 8);
        qf[0] = *(const bf16x8*)(qp);
        qf[1] = *(const bf16x8*)(qp + 32);
    }

    f32x4 acc[4];
    #pragma unroll
    for (int ct = 0; ct < 4; ++ct) acc[ct] = (f32x4){0.f, 0.f, 0.f, 0.f};
    float psum[4];
    #pragma unroll
    for (int r = 0; r < 4; ++r) psum[r] = 0.f;

    // staging: thread owns 16 contiguous bf16 of each 8KB tile
    const int sj = tid >> 2;               // row within tile
    const int sc = (tid & 3) * 16;         // col within row
    const bf16_t* kbase = Kb + ((size_t)bh * Ll) * Ee;
    const bf16_t* vbase = Vt + ((size_t)bh * 32) * 64 * 64;

    for (int k0 = 0; k0 < Ll; k0 += BKV) {
        const int dd = k0 - q0;
        if (dd >= -64 && dd <= 64) continue;          // tile fully masked
        const bool needmask = (dd == 128) || (dd == -128);

        __syncthreads();  // protect LDS from previous iteration's readers
        {
            const bf16_t* kt = kbase + (size_t)k0 * Ee + tid * 16;
            const bf16_t* vt = vbase + (size_t)(k0 >> 6) * 4096 + tid * 16;
            bf16x8 ka = *(const bf16x8*)kt;
            bf16x8 kb2 = *(const bf16x8*)(kt + 8);
            bf16x8 va = *(const bf16x8*)vt;
            bf16x8 vb = *(const bf16x8*)(vt + 8);
            *(bf16x8*)&Klds[SWZ(sj, sc)]      = ka;
            *(bf16x8*)&Klds[SWZ(sj, sc + 8)]  = kb2;
            *(bf16x8*)&Vtlds[SWZ(sj, sc)]     = va;
            *(bf16x8*)&Vtlds[SWZ(sj, sc + 8)] = vb;
        }
        __syncthreads();

        // S = Q K^T : wave computes 16x64; D layout row=g*4+r, col=16*ct+l15
        f32x4 s[4];
        #pragma unroll
        for (int ct = 0; ct < 4; ++ct) {
            f32x4 z = (f32x4){0.f, 0.f, 0.f, 0.f};
            #pragma unroll
            for (int ks = 0; ks < 2; ++ks) {
                bf16x8 kf = *(const bf16x8*)&Klds[SWZ(ct * 16 + l15, ks * 32 + g * 8)];
                z = MFMA16(qf[ks], kf, z);
            }
            s[ct] = z;
        }

        if (needmask) {
            const int irow = q0 + wv * 16 + g * 4;
            #pragma unroll
            for (int ct = 0; ct < 4; ++ct) {
                const int j = k0 + ct * 16 + l15;
                #pragma unroll
                for (int r = 0; r < 4; ++r) {
                    int diff = irow + r - j;
                    diff = diff < 0 ? -diff : diff;
                    if (diff < MS) s[ct][r] = -1e30f;
                }
            }
        }

        // fixed-max softmax numerator: p = exp2(s); lane-local partial row sums
        #pragma unroll
        for (int ct = 0; ct < 4; ++ct) {
            #pragma unroll
            for (int r = 0; r < 4; ++r) {
                float p = exp2f(s[ct][r]);
                bf16_t pb = (bf16_t)p;
                Plds[wv * 1024 + SWZ(g * 4 + r, ct * 16 + l15)] = pb;
                psum[r] += (float)pb;   // sum exactly what we multiply by
            }
        }

        // P is per-wave; intra-wave LDS ordering (lgkmcnt) suffices — no barrier.

        // O += P V
        #pragma unroll
        for (int ks = 0; ks < 2; ++ks) {
            bf16x8 pf = *(const bf16x8*)&Plds[wv * 1024 + SWZ(l15, ks * 32 + g * 8)];
            #pragma unroll
            for (int ct = 0; ct < 4; ++ct) {
                bf16x8 vf = *(const bf16x8*)&Vtlds[SWZ(ct * 16 + l15, ks * 32 + g * 8)];
                acc[ct] = MFMA16(pf, vf, acc[ct]);
            }
        }
    }

    // epilogue: one shuffle-reduce of the row sums, then O = acc / lsum
    #pragma unroll
    for (int r = 0; r < 4; ++r) {
        float t = psum[r];
        #pragma unroll
        for (int off = 1; off < 16; off <<= 1) t += __shfl_xor(t, off);
        const float inv = 1.0f / t;
        const size_t row = (size_t)(b * Ll + q0 + wv * 16 + g * 4 + r);
        float* op = O + (row * Hh + h) * Dd;
        #pragma unroll
        for (int ct = 0; ct < 4; ++ct)
            op[ct * 16 + l15] = acc[ct][r] * inv;
    }
}

// ---------------- fallback (fp32 inputs, online softmax) ----------------
__global__ __launch_bounds__(256, 2) void fattn_f32(const float* __restrict__ Q,
                                                    const float* __restrict__ K,
                                                    const float* __restrict__ V,
                                                    float* __restrict__ O) {
    __shared__ __align__(16) bf16_t Klds[BKV][LDP];
    __shared__ __align__(16) bf16_t Vtlds[Dd][LDP];
    __shared__ __align__(16) bf16_t Plds[4][16][LDP];

    const int tid = threadIdx.x;
    const int wv  = tid >> 6;
    const int ln  = tid & 63;
    const int l15 = ln & 15;
    const int g   = ln >> 4;

    const int nqt = Ll / BQ;
    const int bid = blockIdx.x;
    const int qt  = bid % nqt;
    const int bh  = bid / nqt;
    const int b   = bh >> 3;
    const int h   = bh & 7;
    const int q0  = qt * BQ;

    const float SCL2 = 0.125f * 1.44269504f;

    bf16x8 qf[2];
    {
        const float* qp = Q + (((size_t)(b * Ll + q0 + wv * 16 + l15)) * Hh + h) * Ee + g * 8;
        #pragma unroll
        for (int ks = 0; ks < 2; ++ks) {
            float4 f0 = *(const float4*)(qp + 32 * ks);
            float4 f1 = *(const float4*)(qp + 32 * ks + 4);
            qf[ks] = cvt8(f0, f1);
        }
    }

    f32x4 acc[4];
    #pragma unroll
    for (int ct = 0; ct < 4; ++ct) acc[ct] = (f32x4){0.f, 0.f, 0.f, 0.f};
    float m2[4], lsum[4];
    #pragma unroll
    for (int r = 0; r < 4; ++r) { m2[r] = -1e30f; lsum[r] = 0.f; }

    for (int k0 = 0; k0 < Ll; k0 += BKV) {
        const int dd = k0 - q0;
        if (dd >= -64 && dd <= 64) continue;
        const bool needmask = (dd == 128) || (dd == -128);

        __syncthreads();
        {
            const int j  = tid >> 2;
            const int c0 = (tid & 3) << 4;
            const float* kp = K + (((size_t)(b * Ll + k0 + j)) * Hh + h) * Ee + c0;
            const float* vp = V + (((size_t)(b * Ll + k0 + j)) * Hh + h) * Dd + c0;
            float4 a0 = ((const float4*)kp)[0], a1 = ((const float4*)kp)[1];
            float4 a2 = ((const float4*)kp)[2], a3 = ((const float4*)kp)[3];
            *(bf16x8*)&Klds[j][c0]     = cvt8(a0, a1);
            *(bf16x8*)&Klds[j][c0 + 8] = cvt8(a2, a3);
            float4 b0 = ((const float4*)vp)[0], b1 = ((const float4*)vp)[1];
            float4 b2 = ((const float4*)vp)[2], b3 = ((const float4*)vp)[3];
            Vtlds[c0 +  0][j] = (bf16_t)b0.x; Vtlds[c0 +  1][j] = (bf16_t)b0.y;
            Vtlds[c0 +  2][j] = (bf16_t)b0.z; Vtlds[c0 +  3][j] = (bf16_t)b0.w;
            Vtlds[c0 +  4][j] = (bf16_t)b1.x; Vtlds[c0 +  5][j] = (bf16_t)b1.y;
            Vtlds[c0 +  6][j] = (bf16_t)b1.z; Vtlds[c0 +  7][j] = (bf16_t)b1.w;
            Vtlds[c0 +  8][j] = (bf16_t)b2.x; Vtlds[c0 +  9][j] = (bf16_t)b2.y;
            Vtlds[c0 + 10][j] = (bf16_t)b2.z; Vtlds[c0 + 11][j] = (bf16_t)b2.w;
            Vtlds[c0 + 12][j] = (bf16_t)b3.x; Vtlds[c0 + 13][j] = (bf16_t)b3.y;
            Vtlds[c0 + 14][j] = (bf16_t)b3.z; Vtlds[c0 + 15][j] = (bf16_t)b3.w;
        }
        __syncthreads();

        f32x4 s[4];
        #pragma unroll
        for (int ct = 0; ct < 4; ++ct) {
            f32x4 z = (f32x4){0.f, 0.f, 0.f, 0.f};
            #pragma unroll
            for (int ks = 0; ks < 2; ++ks) {
                bf16x8 kf = *(const bf16x8*)&Klds[ct * 16 + l15][ks * 32 + g * 8];
                z = MFMA16(qf[ks], kf, z);
            }
            s[ct] = z;
        }

        float lg[4][4];
        #pragma unroll
        for (int ct = 0; ct < 4; ++ct)
            #pragma unroll
            for (int r = 0; r < 4; ++r)
                lg[ct][r] = s[ct][r] * SCL2;

        if (needmask) {
            const int irow = q0 + wv * 16 + g * 4;
            #pragma unroll
            for (int ct = 0; ct < 4; ++ct) {
                const int j = k0 + ct * 16 + l15;
                #pragma unroll
                for (int r = 0; r < 4; ++r) {
                    int diff = irow + r - j;
                    diff = diff < 0 ? -diff : diff;
                    if (diff < MS) lg[ct][r] = -1e30f;
                }
            }
        }

        #pragma unroll
        for (int r = 0; r < 4; ++r) {
            float mx = fmaxf(fmaxf(lg[0][r], lg[1][r]), fmaxf(lg[2][r], lg[3][r]));
            #pragma unroll
            for (int off = 1; off < 16; off <<= 1) mx = fmaxf(mx, __shfl_xor(mx, off));
            const float mnew = fmaxf(m2[r], mx);
            const float c = exp2f(m2[r] - mnew);
            m2[r] = mnew;
            #pragma unroll
            for (int ct = 0; ct < 4; ++ct) acc[ct][r] *= c;
            float ps = 0.f;
            #pragma unroll
            for (int ct = 0; ct < 4; ++ct) {
                float p = exp2f(lg[ct][r] - mnew);
                bf16_t pb = (bf16_t)p;
                Plds[wv][g * 4 + r][ct * 16 + l15] = pb;
                ps += (float)pb;
            }
            #pragma unroll
            for (int off = 1; off < 16; off <<= 1) ps += __shfl_xor(ps, off);
            lsum[r] = lsum[r] * c + ps;
        }

        __syncthreads();

        #pragma unroll
        for (int ks = 0; ks < 2; ++ks) {
            bf16x8 pf = *(const bf16x8*)&Plds[wv][l15][ks * 32 + g * 8];
            #pragma unroll
            for (int ct = 0; ct < 4; ++ct) {
                bf16x8 vf = *(const bf16x8*)&Vtlds[ct * 16 + l15][ks * 32 + g * 8];
                acc[ct] = MFMA16(pf, vf, acc[ct]);
            }
        }
    }

    #pragma unroll
    for (int r = 0; r < 4; ++r) {
        const float inv = 1.0f / lsum[r];
        const size_t row = (size_t)(b * Ll + q0 + wv * 16 + g * 4 + r);
        float* op = O + (row * Hh + h) * Dd;
        #pragma unroll
        for (int ct = 0; ct < 4; ++ct)
            op[ct * 16 + l15] = acc[ct][r] * inv;
    }
}

extern "C" void kernel_launch(void* const* d_in, const int* in_sizes, int n_in,
                              void* d_out, int out_size, void* d_ws, size_t ws_size,
                              hipStream_t stream) {
    const float* Q = (const float*)d_in[0];
    const float* K = (const float*)d_in[1];
    const float* V = (const float*)d_in[2];
    float* O = (float*)d_out;
    const int nblocks = Bb * Hh * (Ll / BQ);  // 1024

    const size_t nelem = (size_t)Bb * Hh * Ll * Ee;      // 4.19M per tensor
    const size_t need  = nelem * 2 * 3;                  // 3 bf16 tensors

    if (ws_size >= need) {
        bf16_t* Qb = (bf16_t*)d_ws;
        bf16_t* Kb = Qb + nelem;
        bf16_t* Vt = Kb + nelem;
        const int cblocks = (int)(nelem / 8 / 256);      // 2048
        const float SCL2 = 0.125f * 1.44269504f;         // (1/sqrt(64))*log2(e)
        cvt_qk<<<dim3(cblocks), dim3(256), 0, stream>>>(Q, Qb, SCL2);
        cvt_qk<<<dim3(cblocks), dim3(256), 0, stream>>>(K, Kb, 1.0f);
        cvt_v<<<dim3(Bb * Hh * 32), dim3(256), 0, stream>>>(V, Vt);
        fattn_bf<<<dim3(nblocks), dim3(256), 0, stream>>>(Qb, Kb, Vt, O);
    } else {
        fattn_f32<<<dim3(nblocks), dim3(256), 0, stream>>>(Q, K, V, O);
    }
}

// Round 4
// 73.315 us; speedup vs baseline: 1.9887x; 1.1703x over previous
//
#include <hip/hip_runtime.h>
#include <hip/hip_bf16.h>

typedef __bf16 bf16_t;
typedef __bf16 bf16x8 __attribute__((ext_vector_type(8)));
typedef float f32x4 __attribute__((ext_vector_type(4)));
typedef float f32x16 __attribute__((ext_vector_type(16)));
typedef unsigned int u32;

#define MFMA16(A,B,C) __builtin_amdgcn_mfma_f32_16x16x32_bf16(A,B,C,0,0,0)
#define MFMA32(A,B,C) __builtin_amdgcn_mfma_f32_32x32x16_bf16(A,B,C,0,0,0)

constexpr int Bb = 4, Ll = 2048, Hh = 8, Ee = 64, Dd = 64;
constexpr int LDP = 72;   // fallback kernels only
constexpr int MS = 128;   // band half-width (masked to -inf inside band)

static __device__ __forceinline__ bf16x8 cvt8(float4 a, float4 b) {
    bf16x8 t;
    t[0] = (bf16_t)a.x; t[1] = (bf16_t)a.y; t[2] = (bf16_t)a.z; t[3] = (bf16_t)a.w;
    t[4] = (bf16_t)b.x; t[5] = (bf16_t)b.y; t[6] = (bf16_t)b.z; t[7] = (bf16_t)b.w;
    return t;
}

static __device__ __forceinline__ u32 pkbf(float lo, float hi) {
    u32 d;
    asm("v_cvt_pk_bf16_f32 %0, %1, %2" : "=v"(d) : "v"(lo), "v"(hi));
    return d;
}

static __device__ __forceinline__ f32x16 zero16() {
    f32x16 z;
    #pragma unroll
    for (int r = 0; r < 16; ++r) z[r] = 0.f;
    return z;
}

// ---------------- prep: Q and K [b,l,h,e] fp32 -> [b,h,l,e] bf16 ------------
// First 2048 blocks: Q (scaled by (1/8)*log2e). Next 2048: K (unscaled).
__global__ __launch_bounds__(256) void cvt_qk2(const float* __restrict__ Q,
                                               const float* __restrict__ K,
                                               bf16_t* __restrict__ Qb,
                                               bf16_t* __restrict__ Kb) {
    const bool isK = blockIdx.x >= 2048;
    const int c = (blockIdx.x - (isK ? 2048 : 0)) * 256 + threadIdx.x;
    const float scale = isK ? 1.0f : (0.125f * 1.44269504f);
    const float* src = isK ? K : Q;
    bf16_t* dst = isK ? Kb : Qb;
    const int e0 = (c & 7) * 8;
    const int h  = (c >> 3) & (Hh - 1);
    const int l  = (c >> 6) & (Ll - 1);
    const int b  = c >> 17;
    const float* s = src + ((((size_t)b * Ll + l) * Hh + h) * Ee + e0);
    float4 f0 = ((const float4*)s)[0];
    float4 f1 = ((const float4*)s)[1];
    f0.x *= scale; f0.y *= scale; f0.z *= scale; f0.w *= scale;
    f1.x *= scale; f1.y *= scale; f1.z *= scale; f1.w *= scale;
    *(bf16x8*)(dst + ((((size_t)b * Hh + h) * Ll + l) * Ee + e0)) = cvt8(f0, f1);
}

// -------- prep: V [b,l,h,d] fp32 -> Vt [b,h,tile,d,64] bf16 (transposed) ----
__global__ __launch_bounds__(256) void cvt_v(const float* __restrict__ V,
                                             bf16_t* __restrict__ Vt) {
    __shared__ bf16_t VLp[Dd][LDP];
    const int bh = blockIdx.x >> 5;
    const int t  = blockIdx.x & 31;
    const int b = bh >> 3, h = bh & 7;
    {
        const int j  = threadIdx.x >> 2;
        const int d0 = (threadIdx.x & 3) * 16;
        const float* vp = V + (((size_t)(b * Ll + t * 64 + j)) * Hh + h) * Dd + d0;
        float4 x0 = ((const float4*)vp)[0], x1 = ((const float4*)vp)[1];
        float4 x2 = ((const float4*)vp)[2], x3 = ((const float4*)vp)[3];
        VLp[d0 +  0][j] = (bf16_t)x0.x; VLp[d0 +  1][j] = (bf16_t)x0.y;
        VLp[d0 +  2][j] = (bf16_t)x0.z; VLp[d0 +  3][j] = (bf16_t)x0.w;
        VLp[d0 +  4][j] = (bf16_t)x1.x; VLp[d0 +  5][j] = (bf16_t)x1.y;
        VLp[d0 +  6][j] = (bf16_t)x1.z; VLp[d0 +  7][j] = (bf16_t)x1.w;
        VLp[d0 +  8][j] = (bf16_t)x2.x; VLp[d0 +  9][j] = (bf16_t)x2.y;
        VLp[d0 + 10][j] = (bf16_t)x2.z; VLp[d0 + 11][j] = (bf16_t)x2.w;
        VLp[d0 + 12][j] = (bf16_t)x3.x; VLp[d0 + 13][j] = (bf16_t)x3.y;
        VLp[d0 + 14][j] = (bf16_t)x3.z; VLp[d0 + 15][j] = (bf16_t)x3.w;
    }
    __syncthreads();
    {
        const int d  = threadIdx.x >> 2;
        const int j0 = (threadIdx.x & 3) * 16;
        bf16x8 a0 = *(const bf16x8*)&VLp[d][j0];
        bf16x8 a1 = *(const bf16x8*)&VLp[d][j0 + 8];
        bf16_t* op = Vt + ((((size_t)bh * 32 + t) * 64 + d) * 64 + j0);
        *(bf16x8*)op = a0;
        *(bf16x8*)(op + 8) = a1;
    }
}

// ---------------- main: 32x32 swapped-QK^T, in-register P, DMA staging ------
// BQ=128 (4 waves x 32 q-rows), KV tile 64. Grid 512, XCD-swizzled.
__global__ __launch_bounds__(256, 2) void fattn2(const bf16_t* __restrict__ Qb,
                                                 const bf16_t* __restrict__ Kb,
                                                 const bf16_t* __restrict__ Vt,
                                                 float* __restrict__ O) {
    __shared__ __align__(16) bf16_t KL[2 * 4096];
    __shared__ __align__(16) bf16_t VL[2 * 4096];

    const int tid = threadIdx.x;
    const int wv  = tid >> 6;
    const int ln  = tid & 63;
    const int l31 = ln & 31;
    const int lh  = ln >> 5;

    // XCD swizzle: 8 XCDs x 64 blocks; each XCD owns 4 consecutive bh
    const int bid = blockIdx.x;
    const int x   = bid & 7;
    const int o   = bid >> 3;             // 0..63
    const int bh  = x * 4 + (o >> 4);     // 0..31
    const int qt  = o & 15;               // 0..15
    const int q0  = qt * 128;
    const int wq0 = q0 + wv * 32;
    const int qq  = wq0 + l31;            // this lane's query row

    const int b = bh >> 3, h = bh & 7;

    const bf16_t* kbase = Kb + (size_t)bh * (Ll * 64);
    const bf16_t* vbase = Vt + (size_t)bh * (Ll * 64);

    // Q B-fragments: lane holds q-row qq; qreg[ks] = e in [ks*16+8*lh, +8)
    bf16x8 qreg[4];
    {
        const bf16_t* qp = Qb + ((size_t)bh * Ll + qq) * 64 + lh * 8;
        qreg[0] = *(const bf16x8*)(qp);
        qreg[1] = *(const bf16x8*)(qp + 16);
        qreg[2] = *(const bf16x8*)(qp + 32);
        qreg[3] = *(const bf16x8*)(qp + 48);
    }

    f32x16 acc0 = zero16(), acc1 = zero16();
    float psum = 0.f;

    // staging: per wave 4 x global_load_lds(16B); source pre-swizzled so that
    // the linear DMA write realizes chunk-XOR swizzle in LDS (chunk ^= row&7)
    const int rowoff = (ln >> 3) * 64 + (((ln & 7) ^ (ln >> 3)) * 8);
    const int i0 = (wv & 1) * 4;                       // first sub-call (rows i0*8..)
    const bf16_t* gsb = (wv < 2) ? kbase : vbase;
    bf16_t* lsb = (wv < 2) ? KL : VL;

    const int s0t = q0 >> 6;   // tiles s0t, s0t+1 are fully inside the band -> skipped
    constexpr int NT = 30;     // always exactly 30 live tiles

    #define STAGE(nxt, kt_) do {                                                   \
        const bf16_t* _g = gsb + (kt_) * 4096 + i0 * 512 + rowoff;                 \
        bf16_t* _l = lsb + (nxt) * 4096 + i0 * 512;                                \
        _Pragma("unroll")                                                          \
        for (int _c = 0; _c < 4; ++_c)                                             \
            __builtin_amdgcn_global_load_lds((const void*)(_g + _c * 512),         \
                                             (void*)(_l + _c * 512), 16, 0, 0);    \
    } while (0)

    STAGE(0, (0 >= s0t ? 2 : 0));

    for (int i = 0; i < NT; ++i) {
        const int kt_ = i + (i >= s0t ? 2 : 0);
        const int k0 = kt_ * 64;

        if (i + 1 < NT) {
            const int ktn = (i + 1) + ((i + 1) >= s0t ? 2 : 0);
            STAGE((i + 1) & 1, ktn);
            asm volatile("s_waitcnt vmcnt(4)" ::: "memory");
        } else {
            asm volatile("s_waitcnt vmcnt(0)" ::: "memory");
        }
        __builtin_amdgcn_s_barrier();

        const int bo = (i & 1) * 4096;

        // ---- S^T = K Q^T : two 32x32 subtiles (k-rows [0,32) and [32,64)) ----
        f32x16 s0v = zero16(), s1v = zero16();
        #pragma unroll
        for (int ks = 0; ks < 4; ++ks) {
            const int cc = (((2 * ks + lh) ^ (l31 & 7)) << 3);
            bf16x8 ka0 = *(const bf16x8*)&KL[bo + l31 * 64 + cc];
            bf16x8 ka1 = *(const bf16x8*)&KL[bo + (32 + l31) * 64 + cc];
            s0v = MFMA32(ka0, qreg[ks], s0v);
            s1v = MFMA32(ka1, qreg[ks], s1v);
        }

        // ---- band mask (only tiles straddling the band edge) ----
        {
            const int d0_ = wq0 - k0;
            if (d0_ > -159 && d0_ < 159) {
                #pragma unroll
                for (int r = 0; r < 16; ++r) {
                    const int k = k0 + 4 * lh + ((r & 3) + 8 * (r >> 2));
                    const int dlt = qq - k;
                    if (dlt > -MS && dlt < MS) s0v[r] = -1e30f;
                }
            }
            const int d1_ = wq0 - (k0 + 32);
            if (d1_ > -159 && d1_ < 159) {
                #pragma unroll
                for (int r = 0; r < 16; ++r) {
                    const int k = k0 + 32 + 4 * lh + ((r & 3) + 8 * (r >> 2));
                    const int dlt = qq - k;
                    if (dlt > -MS && dlt < MS) s1v[r] = -1e30f;
                }
            }
        }

        // ---- fixed-max softmax numerator + T12 pack into PV A-fragments ----
        bf16x8 pf[4];
        {
            float p[16];
            #pragma unroll
            for (int r = 0; r < 16; ++r) { p[r] = exp2f(s0v[r]); psum += p[r]; }
            u32 x0 = pkbf(p[0], p[1]),   x1 = pkbf(p[2], p[3]);
            u32 x2 = pkbf(p[4], p[5]),   x3 = pkbf(p[6], p[7]);
            u32 x4 = pkbf(p[8], p[9]),   x5 = pkbf(p[10], p[11]);
            u32 x6 = pkbf(p[12], p[13]), x7 = pkbf(p[14], p[15]);
            asm volatile("v_permlane32_swap_b32 %0, %1" : "+v"(x0), "+v"(x2));
            asm volatile("v_permlane32_swap_b32 %0, %1" : "+v"(x1), "+v"(x3));
            asm volatile("v_permlane32_swap_b32 %0, %1" : "+v"(x4), "+v"(x6));
            asm volatile("v_permlane32_swap_b32 %0, %1" : "+v"(x5), "+v"(x7));
            union { u32 w[4]; bf16x8 v; } u0, u1;
            u0.w[0] = x0; u0.w[1] = x1; u0.w[2] = x2; u0.w[3] = x3;
            u1.w[0] = x4; u1.w[1] = x5; u1.w[2] = x6; u1.w[3] = x7;
            pf[0] = u0.v; pf[1] = u1.v;
        }
        {
            float p[16];
            #pragma unroll
            for (int r = 0; r < 16; ++r) { p[r] = exp2f(s1v[r]); psum += p[r]; }
            u32 x0 = pkbf(p[0], p[1]),   x1 = pkbf(p[2], p[3]);
            u32 x2 = pkbf(p[4], p[5]),   x3 = pkbf(p[6], p[7]);
            u32 x4 = pkbf(p[8], p[9]),   x5 = pkbf(p[10], p[11]);
            u32 x6 = pkbf(p[12], p[13]), x7 = pkbf(p[14], p[15]);
            asm volatile("v_permlane32_swap_b32 %0, %1" : "+v"(x0), "+v"(x2));
            asm volatile("v_permlane32_swap_b32 %0, %1" : "+v"(x1), "+v"(x3));
            asm volatile("v_permlane32_swap_b32 %0, %1" : "+v"(x4), "+v"(x6));
            asm volatile("v_permlane32_swap_b32 %0, %1" : "+v"(x5), "+v"(x7));
            union { u32 w[4]; bf16x8 v; } u0, u1;
            u0.w[0] = x0; u0.w[1] = x1; u0.w[2] = x2; u0.w[3] = x3;
            u1.w[0] = x4; u1.w[1] = x5; u1.w[2] = x6; u1.w[3] = x7;
            pf[2] = u0.v; pf[3] = u1.v;
        }

        // ---- O += P V : lane owns d-col l31 (+32), q-rows in regs ----
        #pragma unroll
        for (int ks = 0; ks < 4; ++ks) {
            const int cc = (((2 * ks + lh) ^ (l31 & 7)) << 3);
            bf16x8 vf0 = *(const bf16x8*)&VL[bo + l31 * 64 + cc];
            bf16x8 vf1 = *(const bf16x8*)&VL[bo + (32 + l31) * 64 + cc];
            acc0 = MFMA32(pf[ks], vf0, acc0);
            acc1 = MFMA32(pf[ks], vf1, acc1);
        }

        __builtin_amdgcn_s_barrier();
    }
    #undef STAGE

    // ---- epilogue ----
    psum += __shfl_xor(psum, 32);
    const float inv = 1.0f / psum;
    #pragma unroll
    for (int r = 0; r < 16; ++r) {
        const int rr = (r & 3) + 8 * (r >> 2) + 4 * lh;
        const float ir = __shfl(inv, rr);
        float* op = O + ((size_t)(b * Ll + wq0 + rr) * Hh + h) * Dd + l31;
        op[0]  = acc0[r] * ir;
        op[32] = acc1[r] * ir;
    }
}

// ---------------- fallback (fp32 inputs, online softmax, 16x16) -------------
__global__ __launch_bounds__(256, 2) void fattn_f32(const float* __restrict__ Q,
                                                    const float* __restrict__ K,
                                                    const float* __restrict__ V,
                                                    float* __restrict__ O) {
    __shared__ __align__(16) bf16_t Klds[64][LDP];
    __shared__ __align__(16) bf16_t Vtlds[Dd][LDP];
    __shared__ __align__(16) bf16_t Plds[4][16][LDP];

    const int tid = threadIdx.x;
    const int wv  = tid >> 6;
    const int ln  = tid & 63;
    const int l15 = ln & 15;
    const int g   = ln >> 4;

    const int nqt = Ll / 64;
    const int bid = blockIdx.x;
    const int qt  = bid % nqt;
    const int bh  = bid / nqt;
    const int b   = bh >> 3;
    const int h   = bh & 7;
    const int q0  = qt * 64;

    const float SCL2 = 0.125f * 1.44269504f;

    bf16x8 qf[2];
    {
        const float* qp = Q + (((size_t)(b * Ll + q0 + wv * 16 + l15)) * Hh + h) * Ee + g * 8;
        #pragma unroll
        for (int ks = 0; ks < 2; ++ks) {
            float4 f0 = *(const float4*)(qp + 32 * ks);
            float4 f1 = *(const float4*)(qp + 32 * ks + 4);
            qf[ks] = cvt8(f0, f1);
        }
    }

    f32x4 acc[4];
    #pragma unroll
    for (int ct = 0; ct < 4; ++ct) acc[ct] = (f32x4){0.f, 0.f, 0.f, 0.f};
    float m2[4], lsum[4];
    #pragma unroll
    for (int r = 0; r < 4; ++r) { m2[r] = -1e30f; lsum[r] = 0.f; }

    for (int k0 = 0; k0 < Ll; k0 += 64) {
        const int dd = k0 - q0;
        if (dd >= -64 && dd <= 64) continue;
        const bool needmask = (dd == 128) || (dd == -128);

        __syncthreads();
        {
            const int j  = tid >> 2;
            const int c0 = (tid & 3) << 4;
            const float* kp = K + (((size_t)(b * Ll + k0 + j)) * Hh + h) * Ee + c0;
            const float* vp = V + (((size_t)(b * Ll + k0 + j)) * Hh + h) * Dd + c0;
            float4 a0 = ((const float4*)kp)[0], a1 = ((const float4*)kp)[1];
            float4 a2 = ((const float4*)kp)[2], a3 = ((const float4*)kp)[3];
            *(bf16x8*)&Klds[j][c0]     = cvt8(a0, a1);
            *(bf16x8*)&Klds[j][c0 + 8] = cvt8(a2, a3);
            float4 b0 = ((const float4*)vp)[0], b1 = ((const float4*)vp)[1];
            float4 b2 = ((const float4*)vp)[2], b3 = ((const float4*)vp)[3];
            Vtlds[c0 +  0][j] = (bf16_t)b0.x; Vtlds[c0 +  1][j] = (bf16_t)b0.y;
            Vtlds[c0 +  2][j] = (bf16_t)b0.z; Vtlds[c0 +  3][j] = (bf16_t)b0.w;
            Vtlds[c0 +  4][j] = (bf16_t)b1.x; Vtlds[c0 +  5][j] = (bf16_t)b1.y;
            Vtlds[c0 +  6][j] = (bf16_t)b1.z; Vtlds[c0 +  7][j] = (bf16_t)b1.w;
            Vtlds[c0 +  8][j] = (bf16_t)b2.x; Vtlds[c0 +  9][j] = (bf16_t)b2.y;
            Vtlds[c0 + 10][j] = (bf16_t)b2.z; Vtlds[c0 + 11][j] = (bf16_t)b2.w;
            Vtlds[c0 + 12][j] = (bf16_t)b3.x; Vtlds[c0 + 13][j] = (bf16_t)b3.y;
            Vtlds[c0 + 14][j] = (bf16_t)b3.z; Vtlds[c0 + 15][j] = (bf16_t)b3.w;
        }
        __syncthreads();

        f32x4 s[4];
        #pragma unroll
        for (int ct = 0; ct < 4; ++ct) {
            f32x4 z = (f32x4){0.f, 0.f, 0.f, 0.f};
            #pragma unroll
            for (int ks = 0; ks < 2; ++ks) {
                bf16x8 kf = *(const bf16x8*)&Klds[ct * 16 + l15][ks * 32 + g * 8];
                z = MFMA16(qf[ks], kf, z);
            }
            s[ct] = z;
        }

        float lg[4][4];
        #pragma unroll
        for (int ct = 0; ct < 4; ++ct)
            #pragma unroll
            for (int r = 0; r < 4; ++r)
                lg[ct][r] = s[ct][r] * SCL2;

        if (needmask) {
            const int irow = q0 + wv * 16 + g * 4;
            #pragma unroll
            for (int ct = 0; ct < 4; ++ct) {
                const int j = k0 + ct * 16 + l15;
                #pragma unroll
                for (int r = 0; r < 4; ++r) {
                    int diff = irow + r - j;
                    diff = diff < 0 ? -diff : diff;
                    if (diff < MS) lg[ct][r] = -1e30f;
                }
            }
        }

        #pragma unroll
        for (int r = 0; r < 4; ++r) {
            float mx = fmaxf(fmaxf(lg[0][r], lg[1][r]), fmaxf(lg[2][r], lg[3][r]));
            #pragma unroll
            for (int off = 1; off < 16; off <<= 1) mx = fmaxf(mx, __shfl_xor(mx, off));
            const float mnew = fmaxf(m2[r], mx);
            const float c = exp2f(m2[r] - mnew);
            m2[r] = mnew;
            #pragma unroll
            for (int ct = 0; ct < 4; ++ct) acc[ct][r] *= c;
            float ps = 0.f;
            #pragma unroll
            for (int ct = 0; ct < 4; ++ct) {
                float p = exp2f(lg[ct][r] - mnew);
                bf16_t pb = (bf16_t)p;
                Plds[wv][g * 4 + r][ct * 16 + l15] = pb;
                ps += (float)pb;
            }
            #pragma unroll
            for (int off = 1; off < 16; off <<= 1) ps += __shfl_xor(ps, off);
            lsum[r] = lsum[r] * c + ps;
        }

        __syncthreads();

        #pragma unroll
        for (int ks = 0; ks < 2; ++ks) {
            bf16x8 pfr = *(const bf16x8*)&Plds[wv][l15][ks * 32 + g * 8];
            #pragma unroll
            for (int ct = 0; ct < 4; ++ct) {
                bf16x8 vf = *(const bf16x8*)&Vtlds[ct * 16 + l15][ks * 32 + g * 8];
                acc[ct] = MFMA16(pfr, vf, acc[ct]);
            }
        }
    }

    #pragma unroll
    for (int r = 0; r < 4; ++r) {
        const float inv = 1.0f / lsum[r];
        const size_t row = (size_t)(b * Ll + q0 + wv * 16 + g * 4 + r);
        float* op = O + (row * Hh + h) * Dd;
        #pragma unroll
        for (int ct = 0; ct < 4; ++ct)
            op[ct * 16 + l15] = acc[ct][r] * inv;
    }
}

extern "C" void kernel_launch(void* const* d_in, const int* in_sizes, int n_in,
                              void* d_out, int out_size, void* d_ws, size_t ws_size,
                              hipStream_t stream) {
    const float* Q = (const float*)d_in[0];
    const float* K = (const float*)d_in[1];
    const float* V = (const float*)d_in[2];
    float* O = (float*)d_out;

    const size_t nelem = (size_t)Bb * Hh * Ll * Ee;      // 4.19M per tensor
    const size_t need  = nelem * 2 * 3;                  // 3 bf16 tensors

    if (ws_size >= need) {
        bf16_t* Qb = (bf16_t*)d_ws;
        bf16_t* Kb = Qb + nelem;
        bf16_t* Vt = Kb + nelem;
        cvt_qk2<<<dim3(4096), dim3(256), 0, stream>>>(Q, K, Qb, Kb);
        cvt_v<<<dim3(Bb * Hh * 32), dim3(256), 0, stream>>>(V, Vt);
        fattn2<<<dim3(512), dim3(256), 0, stream>>>(Qb, Kb, Vt, O);
    } else {
        fattn_f32<<<dim3(Bb * Hh * 32), dim3(256), 0, stream>>>(Q, K, V, O);
    }
}